// Round 21
// baseline (131.649 us; speedup 1.0000x reference)
//
#include <hip/hip_runtime.h>
#include <hip/hip_bf16.h>

#define H_   16
#define NQ_  2048
#define NK_  2048
#define DM_  1024

typedef float f32x4 __attribute__((ext_vector_type(4)));
typedef float f32x16 __attribute__((ext_vector_type(16)));
typedef __bf16 bf16x8 __attribute__((ext_vector_type(8)));
typedef unsigned short u16x8 __attribute__((ext_vector_type(8)));
typedef unsigned short u16x4 __attribute__((ext_vector_type(4)));

__device__ __forceinline__ unsigned short bfbits(float x) {
  __bf16 h = (__bf16)x;
  return __builtin_bit_cast(unsigned short, h);
}

__device__ __forceinline__ bf16x8 cvt8(float4 a, float4 b) {
  bf16x8 o;
  o[0] = (__bf16)a.x; o[1] = (__bf16)a.y; o[2] = (__bf16)a.z; o[3] = (__bf16)a.w;
  o[4] = (__bf16)b.x; o[5] = (__bf16)b.y; o[6] = (__bf16)b.z; o[7] = (__bf16)b.w;
  return o;
}

// ---------------- prep: 4x fused transpose 1024x1024 f32 -> bf16 (weights only) ----------
__global__ __launch_bounds__(256) void prep(
    const float* __restrict__ s0, const float* __restrict__ s1,
    const float* __restrict__ s2, const float* __restrict__ s3,
    unsigned short* __restrict__ d0, unsigned short* __restrict__ d1,
    unsigned short* __restrict__ d2, unsigned short* __restrict__ d3) {
  const float* src = (blockIdx.z == 0) ? s0 : (blockIdx.z == 1) ? s1 : (blockIdx.z == 2) ? s2 : s3;
  unsigned short* dst = (blockIdx.z == 0) ? d0 : (blockIdx.z == 1) ? d1 : (blockIdx.z == 2) ? d2 : d3;
  __shared__ float t[64][65];
  const int r0 = blockIdx.x * 64, c0 = blockIdx.y * 64;
  for (int i = threadIdx.x; i < 4096; i += 256) {
    int r = i >> 6, c = i & 63;
    t[r][c] = src[(size_t)(r0 + r) * DM_ + c0 + c];
  }
  __syncthreads();
  for (int i = threadIdx.x; i < 4096; i += 256) {
    int n = i >> 6, kk = i & 63;
    dst[(size_t)(c0 + n) * DM_ + r0 + kk] = bfbits(t[kk][n]);
  }
}

__device__ __forceinline__ void gll16(const unsigned short* g, unsigned short* l) {
  __builtin_amdgcn_global_load_lds((const __attribute__((address_space(1))) void*)g,
                                   (__attribute__((address_space(3))) void*)l, 16, 0, 0);
}

// ---------------- 2-phase dbuf bf16 GEMM, 128x128 tile, BK=32, loads-first ---------------
// f32 operand reg-staged with DOUBLE reg sets (static parity, loop unrolled x2): the f32
// loads for tile kt+2 are issued at the TOP of iter kt, gaining the ds_write+gll16 phase
// of flight time before the end-of-iter vmcnt(0) drain. bf16 operand via global_load_lds.
template <int MODE>
__device__ __forceinline__ void gemm128_body(
    int bx, int by,
    const void* __restrict__ Av, const void* __restrict__ Btv, int K,
    const float* __restrict__ bias, const float* __restrict__ mem,
    const float* __restrict__ Wmm, const float* __restrict__ bmm,
    unsigned short* __restrict__ obf,
    unsigned short* Al, unsigned short* Bl) {
  constexpr bool AF32 = (MODE <= 1);
  constexpr bool BF32 = (MODE == 2);
  const int tid = threadIdx.x, lane = tid & 63, w = tid >> 6;
  const int wm = w >> 1, wn = w & 1;
  const int m0 = bx * 128, n0 = by * 128;
  const int lrow = lane >> 2, lcol = (lane & 3) * 8;
  const int fr = lane & 15, fk = (lane >> 4) * 8;
  constexpr int TSZ = 128 * 32;

  f32x4 acc[4][4] = {};

  const size_t aoff = (size_t)(m0 + w * 32 + lrow) * K + lcol;
  const size_t boff = (size_t)(n0 + w * 32 + lrow) * K + lcol;
  const unsigned short* agb = (const unsigned short*)Av + aoff;
  const float*          agf = (const float*)Av + aoff;
  const unsigned short* bgb = (const unsigned short*)Btv + boff;
  const float*          bgf = (const float*)Btv + boff;
  const int os0 = (w * 32 + lrow) * 32 + lcol;
  const int os1 = (w * 32 + lrow + 16) * 32 + lcol;
  const int oa0 = (w * 32) * 32, oa1 = (w * 32 + 16) * 32;
  const size_t s16K = (size_t)16 * K;

  // double reg sets: tile T lives in set (T&1)
  float4 fa0[2], fa1[2], fa2[2], fa3[2];
  float4 fb0[2], fb1[2], fb2[2], fb3[2];

  const int KT = K >> 5;
  // prologue: tile 0 -> set0 -> LDS buf0; tile 1 -> set1 (in flight)
  if constexpr (AF32) {
    fa0[0] = *(const float4*)agf; fa1[0] = *(const float4*)(agf + 4);
    fa2[0] = *(const float4*)(agf + s16K); fa3[0] = *(const float4*)(agf + s16K + 4);
    *(bf16x8*)(Al + os0) = cvt8(fa0[0], fa1[0]);
    *(bf16x8*)(Al + os1) = cvt8(fa2[0], fa3[0]);
    agf += 32;
    fa0[1] = *(const float4*)agf; fa1[1] = *(const float4*)(agf + 4);
    fa2[1] = *(const float4*)(agf + s16K); fa3[1] = *(const float4*)(agf + s16K + 4);
    agf += 32;
  } else {
    gll16(agb, Al + oa0); gll16(agb + s16K, Al + oa1);
    agb += 32;
  }
  if constexpr (BF32) {
    fb0[0] = *(const float4*)bgf; fb1[0] = *(const float4*)(bgf + 4);
    fb2[0] = *(const float4*)(bgf + s16K); fb3[0] = *(const float4*)(bgf + s16K + 4);
    *(bf16x8*)(Bl + os0) = cvt8(fb0[0], fb1[0]);
    *(bf16x8*)(Bl + os1) = cvt8(fb2[0], fb3[0]);
    bgf += 32;
    fb0[1] = *(const float4*)bgf; fb1[1] = *(const float4*)(bgf + 4);
    fb2[1] = *(const float4*)(bgf + s16K); fb3[1] = *(const float4*)(bgf + s16K + 4);
    bgf += 32;
  } else {
    gll16(bgb, Bl + oa0); gll16(bgb + s16K, Bl + oa1);
    bgb += 32;
  }
  __syncthreads();

  // loop unrolled x2 for static reg-set parity (rule #20: no runtime indexing)
#pragma unroll 1
  for (int kt = 0; kt < KT; kt += 2) {
    // ---- even sub-iter: compute buf0; stage tile kt+1 (set1) -> buf1; load kt+2 -> set0
    {
      if (kt + 2 < KT) {  // issue loads FIRST: full-iteration flight before the drain
        if constexpr (AF32) {
          fa0[0] = *(const float4*)agf; fa1[0] = *(const float4*)(agf + 4);
          fa2[0] = *(const float4*)(agf + s16K); fa3[0] = *(const float4*)(agf + s16K + 4);
          agf += 32;
        }
        if constexpr (BF32) {
          fb0[0] = *(const float4*)bgf; fb1[0] = *(const float4*)(bgf + 4);
          fb2[0] = *(const float4*)(bgf + s16K); fb3[0] = *(const float4*)(bgf + s16K + 4);
          bgf += 32;
        }
      }
      if (kt + 1 < KT) {
        if constexpr (AF32) {
          *(bf16x8*)(Al + TSZ + os0) = cvt8(fa0[1], fa1[1]);
          *(bf16x8*)(Al + TSZ + os1) = cvt8(fa2[1], fa3[1]);
        } else {
          gll16(agb, Al + TSZ + oa0); gll16(agb + s16K, Al + TSZ + oa1);
          agb += 32;
        }
        if constexpr (BF32) {
          *(bf16x8*)(Bl + TSZ + os0) = cvt8(fb0[1], fb1[1]);
          *(bf16x8*)(Bl + TSZ + os1) = cvt8(fb2[1], fb3[1]);
        } else {
          gll16(bgb, Bl + TSZ + oa0); gll16(bgb + s16K, Bl + TSZ + oa1);
          bgb += 32;
        }
      }
      bf16x8 af[4], bfr[4];
#pragma unroll
      for (int i = 0; i < 4; ++i)
        af[i] = *(const bf16x8*)&Al[(wm * 64 + i * 16 + fr) * 32 + fk];
#pragma unroll
      for (int j = 0; j < 4; ++j)
        bfr[j] = *(const bf16x8*)&Bl[(wn * 64 + j * 16 + fr) * 32 + fk];
#pragma unroll
      for (int i = 0; i < 4; ++i)
#pragma unroll
        for (int j = 0; j < 4; ++j)
          acc[i][j] = __builtin_amdgcn_mfma_f32_16x16x32_bf16(af[i], bfr[j], acc[i][j], 0, 0, 0);
      __syncthreads();
    }
    // ---- odd sub-iter: compute buf1; stage tile kt+2 (set0) -> buf0; load kt+3 -> set1
    if (kt + 1 < KT) {
      if (kt + 3 < KT) {
        if constexpr (AF32) {
          fa0[1] = *(const float4*)agf; fa1[1] = *(const float4*)(agf + 4);
          fa2[1] = *(const float4*)(agf + s16K); fa3[1] = *(const float4*)(agf + s16K + 4);
          agf += 32;
        }
        if constexpr (BF32) {
          fb0[1] = *(const float4*)bgf; fb1[1] = *(const float4*)(bgf + 4);
          fb2[1] = *(const float4*)(bgf + s16K); fb3[1] = *(const float4*)(bgf + s16K + 4);
          bgf += 32;
        }
      }
      if (kt + 2 < KT) {
        if constexpr (AF32) {
          *(bf16x8*)(Al + os0) = cvt8(fa0[0], fa1[0]);
          *(bf16x8*)(Al + os1) = cvt8(fa2[0], fa3[0]);
        } else {
          gll16(agb, Al + oa0); gll16(agb + s16K, Al + oa1);
          agb += 32;
        }
        if constexpr (BF32) {
          *(bf16x8*)(Bl + os0) = cvt8(fb0[0], fb1[0]);
          *(bf16x8*)(Bl + os1) = cvt8(fb2[0], fb3[0]);
        } else {
          gll16(bgb, Bl + oa0); gll16(bgb + s16K, Bl + oa1);
          bgb += 32;
        }
      }
      bf16x8 af[4], bfr[4];
#pragma unroll
      for (int i = 0; i < 4; ++i)
        af[i] = *(const bf16x8*)&Al[TSZ + (wm * 64 + i * 16 + fr) * 32 + fk];
#pragma unroll
      for (int j = 0; j < 4; ++j)
        bfr[j] = *(const bf16x8*)&Bl[TSZ + (wn * 64 + j * 16 + fr) * 32 + fk];
#pragma unroll
      for (int i = 0; i < 4; ++i)
#pragma unroll
        for (int j = 0; j < 4; ++j)
          acc[i][j] = __builtin_amdgcn_mfma_f32_16x16x32_bf16(af[i], bfr[j], acc[i][j], 0, 0, 0);
      __syncthreads();
    }
  }

#pragma unroll
  for (int i = 0; i < 4; ++i) {
    const int rowb = m0 + wm * 64 + i * 16 + (lane >> 4) * 4;
#pragma unroll
    for (int j = 0; j < 4; ++j) {
      const int col = n0 + wn * 64 + j * 16 + fr;
#pragma unroll
      for (int r = 0; r < 4; ++r) {
        float v = acc[i][j][r];
        int rr = rowb + r;
        if (MODE == 0) {
          int b = rr >> 11, nq = rr & 2047, h = col >> 6, d = col & 63;
          float val = (v + bias[col]) * 0.180336884f;  // 0.125 * log2(e)
          obf[(((size_t)(b * H_ + h)) * NQ_ + nq) * 64 + d] = bfbits(val);
        } else if (MODE == 1) {
          int b = rr >> 11, nk = rr & 2047, h = col >> 6, d = col & 63;
          float gate = mem[b * NK_ + nk] * Wmm[col] + bmm[col];
          float val = (v + bias[col]) * gate;
          obf[(((size_t)(b * H_ + h)) * NK_ + nk) * 64 + d] = bfbits(val);
        } else {
          int b = col >> 11, key = col & 2047, h = rr >> 6, d = rr & 63;
          float gate = mem[b * NK_ + key] * Wmm[rr] + bmm[rr];
          float val = (v + bias[rr]) * gate;
          // swap bits 2<->3 of key so flash's 32x32 PV B-frag (P in regs) lines up with V
          int keyp = (key & ~12) | ((key & 4) << 1) | ((key & 8) >> 1);
          obf[(((size_t)(b * H_ + h)) * 64 + d) * NK_ + keyp] = bfbits(val);
        }
      }
    }
  }
}

// fused Q/K/V projections: 768 blocks (3/CU), f32 inputs read directly
__global__ __launch_bounds__(256) void gemm_qkv3(
    const float* __restrict__ queries, const float* __restrict__ keys,
    const float* __restrict__ values, const unsigned short* __restrict__ WvT,
    const unsigned short* __restrict__ WqT, const unsigned short* __restrict__ WkT,
    const float* __restrict__ bq, const float* __restrict__ bk, const float* __restrict__ bv,
    const float* __restrict__ mem, const float* __restrict__ Wmm, const float* __restrict__ bmm,
    unsigned short* __restrict__ Qp, unsigned short* __restrict__ Kp,
    unsigned short* __restrict__ VpT) {
  __shared__ unsigned short Al[2 * 128 * 32];
  __shared__ unsigned short Bl[2 * 128 * 32];
  const int gid = (blockIdx.x & 7) * 96 + (blockIdx.x >> 3);
  if (gid < 256) {
    gemm128_body<0>(gid >> 3, gid & 7, queries, WqT, 1024, bq, nullptr, nullptr, nullptr,
                    Qp, Al, Bl);
  } else if (gid < 512) {
    int bb = gid - 256;
    gemm128_body<1>(bb >> 3, bb & 7, keys, WkT, 1024, bk, mem, Wmm, bmm, Kp, Al, Bl);
  } else {
    int bb = gid - 512;
    gemm128_body<2>(bb & 7, bb >> 3, WvT, values, 1024, bv, mem, Wmm, bmm, VpT, Al, Bl);
  }
}

// ---------------- out projection: 64x128 tile, BK=32, 2-phase dbuf (512 blocks) ----------
__global__ __launch_bounds__(256) void gemm_out(
    const unsigned short* __restrict__ AO, const unsigned short* __restrict__ WoT,
    const float* __restrict__ bo, float* __restrict__ out) {
  __shared__ unsigned short Al[2 * 64 * 32];
  __shared__ unsigned short Bl[2 * 128 * 32];
  const int b = (blockIdx.x & 7) * 64 + (blockIdx.x >> 3);
  const int bx = b & 63, by = b >> 6;
  const int tid = threadIdx.x, lane = tid & 63, w = tid >> 6;
  const int wm = w >> 1, wn = w & 1;
  const int m0 = bx * 64, n0 = by * 128;
  const int lrow = lane >> 2, lcol = (lane & 3) * 8;
  const int fr = lane & 15, fk = (lane >> 4) * 8;
  const int K = 1024;
  constexpr int TA = 64 * 32, TB = 128 * 32;

  f32x4 acc[2][4] = {};

  const unsigned short* ag = AO + (size_t)(m0 + w * 16 + lrow) * K + lcol;
  const unsigned short* bg = WoT + (size_t)(n0 + w * 32 + lrow) * K + lcol;
  const int oa = (w * 16) * 32;
  const int ob0 = (w * 32) * 32, ob1 = (w * 32 + 16) * 32;
  const size_t s16K = (size_t)16 * K;

  gll16(ag, Al + oa);
  gll16(bg, Bl + ob0); gll16(bg + s16K, Bl + ob1);
  ag += 32; bg += 32;
  __syncthreads();

  for (int kt = 0; kt < 32; ++kt) {
    const int ca = (kt & 1) * TA, cbb = (kt & 1) * TB;
    const int sa = TA - ca, sbb = TB - cbb;
    if (kt + 1 < 32) {
      gll16(ag, Al + sa + oa);
      gll16(bg, Bl + sbb + ob0); gll16(bg + s16K, Bl + sbb + ob1);
      ag += 32; bg += 32;
    }
    bf16x8 af[2], bfr[4];
#pragma unroll
    for (int i = 0; i < 2; ++i)
      af[i] = *(const bf16x8*)&Al[ca + (wm * 32 + i * 16 + fr) * 32 + fk];
#pragma unroll
    for (int j = 0; j < 4; ++j)
      bfr[j] = *(const bf16x8*)&Bl[cbb + (wn * 64 + j * 16 + fr) * 32 + fk];
#pragma unroll
    for (int i = 0; i < 2; ++i)
#pragma unroll
      for (int j = 0; j < 4; ++j)
        acc[i][j] = __builtin_amdgcn_mfma_f32_16x16x32_bf16(af[i], bfr[j], acc[i][j], 0, 0, 0);
    __syncthreads();
  }

#pragma unroll
  for (int i = 0; i < 2; ++i) {
    const int rowb = m0 + wm * 32 + i * 16 + (lane >> 4) * 4;
#pragma unroll
    for (int j = 0; j < 4; ++j) {
      const int col = n0 + wn * 64 + j * 16 + fr;
#pragma unroll
      for (int r = 0; r < 4; ++r)
        out[(size_t)(rowb + r) * DM_ + col] = acc[i][j][r] + bo[col];
    }
  }
}

// ---------------- flash attention v15 (r20, kept): gll16-staged K/V, chunk-swizzled ------
__global__ __launch_bounds__(256, 2) void flash_attn(const unsigned short* __restrict__ Qp,
                                                     const unsigned short* __restrict__ Kp,
                                                     const unsigned short* __restrict__ VpT,
                                                     unsigned short* __restrict__ AO) {
  __shared__ unsigned short KsL[2][128 * 64];
  __shared__ unsigned short VsL[2][64 * 128];

  const int tid = threadIdx.x, lane = tid & 63, w = tid >> 6;
  const int gid = (blockIdx.x & 7) * 64 + (blockIdx.x >> 3);
  const int bh = gid >> 4;
  const int qt = gid & 15;
  const int r31 = lane & 31, hi2 = lane >> 5, rx7 = lane & 7;

  const unsigned short* qg = Qp + (((size_t)bh * NQ_) + qt * 128 + w * 32 + r31) * 64 + hi2 * 8;
  bf16x8 qf[4];
#pragma unroll
  for (int s = 0; s < 4; ++s) qf[s] = *(const bf16x8*)&qg[s * 16];

  int koff[4], voff[8];
#pragma unroll
  for (int s = 0; s < 4; ++s) koff[s] = ((s * 2 + hi2) ^ rx7) * 8;
#pragma unroll
  for (int ks = 0; ks < 8; ++ks) voff[ks] = ((ks * 2 + hi2) ^ rx7) * 8;

  const int kchunk = (lane & 7) ^ ((lane >> 3) & 7);
  const unsigned short* kgB = Kp + (size_t)bh * NK_ * 64
                              + (size_t)(w * 32 + (lane >> 3)) * 64 + kchunk * 8;
  const int vce = (lane & 15) ^ (lane >> 4);
  const int vco = (lane & 15) ^ (4 + (lane >> 4));
  const unsigned short* vgB = VpT + (size_t)bh * 64 * NK_
                              + (size_t)(w * 16 + (lane >> 4)) * NK_;

#pragma unroll
  for (int i = 0; i < 4; ++i) {
    gll16(kgB + i * 512, &KsL[0][(w * 32 + i * 8) * 64]);
    const int vc = (i & 1) ? vco : vce;
    gll16(vgB + (size_t)i * 4 * NK_ + vc * 8, &VsL[0][(w * 16 + i * 4) * 128]);
  }
  __syncthreads();

  f32x16 acc0 = {}, acc1 = {};
  float l_run = 0.0f;

  for (int kt = 0; kt < 16; ++kt) {
    const int cur = kt & 1;
    if (kt + 1 < 16) {
      const size_t ko = (size_t)(kt + 1) * 128 * 64;
      const int vko = (kt + 1) * 128;
#pragma unroll
      for (int i = 0; i < 4; ++i) {
        gll16(kgB + ko + i * 512, &KsL[cur ^ 1][(w * 32 + i * 8) * 64]);
        const int vc = (i & 1) ? vco : vce;
        gll16(vgB + (size_t)i * 4 * NK_ + vko + vc * 8, &VsL[cur ^ 1][(w * 16 + i * 4) * 128]);
      }
    }

    f32x16 sv[4] = {};
    __builtin_amdgcn_s_setprio(1);
#pragma unroll
    for (int s = 0; s < 4; ++s) {
#pragma unroll
      for (int kb = 0; kb < 4; ++kb) {
        bf16x8 ka = *(const bf16x8*)&KsL[cur][(kb * 32 + r31) * 64 + koff[s]];
        sv[kb] = __builtin_amdgcn_mfma_f32_32x32x16_bf16(ka, qf[s], sv[kb], 0, 0, 0);
      }
    }
    __builtin_amdgcn_s_setprio(0);

    float psp[4] = {0.f, 0.f, 0.f, 0.f};
    bf16x8 pb[8];
#pragma unroll
    for (int kb = 0; kb < 4; ++kb) {
#pragma unroll
      for (int g = 0; g < 16; ++g) {
        float p = __builtin_amdgcn_exp2f(sv[kb][g]);
        psp[kb] += p;
        pb[2 * kb + (g >> 3)][g & 7] = (__bf16)p;
      }
    }
    float ps = (psp[0] + psp[1]) + (psp[2] + psp[3]);
    ps += __shfl_xor(ps, 32);
    l_run += ps;

    __builtin_amdgcn_s_setprio(1);
#pragma unroll
    for (int ks = 0; ks < 8; ++ks) {
      bf16x8 va0 = *(const bf16x8*)&VsL[cur][r31 * 128 + voff[ks]];
      bf16x8 va1 = *(const bf16x8*)&VsL[cur][(32 + r31) * 128 + voff[ks]];
      acc0 = __builtin_amdgcn_mfma_f32_32x32x16_bf16(va0, pb[ks], acc0, 0, 0, 0);
      acc1 = __builtin_amdgcn_mfma_f32_32x32x16_bf16(va1, pb[ks], acc1, 0, 0, 0);
    }
    __builtin_amdgcn_s_setprio(0);

    __syncthreads();
  }

  const int b = bh >> 4, h = bh & 15;
  const float linv = 1.0f / l_run;
  const int qrow = qt * 128 + w * 32 + r31;
  const size_t rowbase = (((size_t)b * NQ_ + qrow) << 10) + h * 64;
#pragma unroll
  for (int c = 0; c < 4; ++c) {
    u16x4 o0, o1;
#pragma unroll
    for (int i = 0; i < 4; ++i) {
      o0[i] = bfbits(acc0[c * 4 + i] * linv);
      o1[i] = bfbits(acc1[c * 4 + i] * linv);
    }
    *(u16x4*)&AO[rowbase + 8 * c + 4 * hi2]      = o0;
    *(u16x4*)&AO[rowbase + 32 + 8 * c + 4 * hi2] = o1;
  }
}

extern "C" void kernel_launch(void* const* d_in, const int* in_sizes, int n_in,
                              void* d_out, int out_size, void* d_ws, size_t ws_size,
                              hipStream_t stream) {
  const float* queries = (const float*)d_in[0];
  const float* keys    = (const float*)d_in[1];
  const float* values  = (const float*)d_in[2];
  const float* memory  = (const float*)d_in[3];
  const float* Wq  = (const float*)d_in[4];
  const float* bq  = (const float*)d_in[5];
  const float* Wk  = (const float*)d_in[6];
  const float* bk  = (const float*)d_in[7];
  const float* Wv  = (const float*)d_in[8];
  const float* bv  = (const float*)d_in[9];
  const float* Wo  = (const float*)d_in[10];
  const float* bo  = (const float*)d_in[11];
  const float* Wmm = (const float*)d_in[12];
  const float* bmm = (const float*)d_in[13];

  char* ws = (char*)d_ws;
  const size_t MB = 1024 * 1024;
  unsigned short* AO  = (unsigned short*)(ws);
  unsigned short* WqT = (unsigned short*)(ws + 8 * MB);
  unsigned short* WkT = (unsigned short*)(ws + 10 * MB);
  unsigned short* WvT = (unsigned short*)(ws + 12 * MB);
  unsigned short* WoT = (unsigned short*)(ws + 14 * MB);
  unsigned short* Qp  = (unsigned short*)(ws + 16 * MB);
  unsigned short* Kp  = (unsigned short*)(ws + 24 * MB);
  unsigned short* VpT = (unsigned short*)(ws + 32 * MB);

  prep<<<dim3(16, 16, 4), 256, 0, stream>>>(Wq, Wk, Wv, Wo, WqT, WkT, WvT, WoT);

  gemm_qkv3<<<768, 256, 0, stream>>>(queries, keys, values, WvT, WqT, WkT,
                                     bq, bk, bv, memory, Wmm, bmm, Qp, Kp, VpT);

  flash_attn<<<512, 256, 0, stream>>>(Qp, Kp, VpT, AO);

  gemm_out<<<512, 256, 0, stream>>>(AO, WoT, bo, (float*)d_out);
}

// Round 22
// 119.100 us; speedup vs baseline: 1.1054x; 1.1054x over previous
//
#include <hip/hip_runtime.h>
#include <hip/hip_bf16.h>

#define H_   16
#define NQ_  2048
#define NK_  2048
#define DM_  1024

typedef float f32x4 __attribute__((ext_vector_type(4)));
typedef float f32x16 __attribute__((ext_vector_type(16)));
typedef __bf16 bf16x8 __attribute__((ext_vector_type(8)));
typedef unsigned short u16x8 __attribute__((ext_vector_type(8)));
typedef unsigned short u16x4 __attribute__((ext_vector_type(4)));

__device__ __forceinline__ unsigned short bfbits(float x) {
  __bf16 h = (__bf16)x;
  return __builtin_bit_cast(unsigned short, h);
}

__device__ __forceinline__ bf16x8 cvt8(float4 a, float4 b) {
  bf16x8 o;
  o[0] = (__bf16)a.x; o[1] = (__bf16)a.y; o[2] = (__bf16)a.z; o[3] = (__bf16)a.w;
  o[4] = (__bf16)b.x; o[5] = (__bf16)b.y; o[6] = (__bf16)b.z; o[7] = (__bf16)b.w;
  return o;
}

// ---------------- prep: 4x fused transpose 1024x1024 f32 -> bf16 (weights only) ----------
__global__ __launch_bounds__(256) void prep(
    const float* __restrict__ s0, const float* __restrict__ s1,
    const float* __restrict__ s2, const float* __restrict__ s3,
    unsigned short* __restrict__ d0, unsigned short* __restrict__ d1,
    unsigned short* __restrict__ d2, unsigned short* __restrict__ d3) {
  const float* src = (blockIdx.z == 0) ? s0 : (blockIdx.z == 1) ? s1 : (blockIdx.z == 2) ? s2 : s3;
  unsigned short* dst = (blockIdx.z == 0) ? d0 : (blockIdx.z == 1) ? d1 : (blockIdx.z == 2) ? d2 : d3;
  __shared__ float t[64][65];
  const int r0 = blockIdx.x * 64, c0 = blockIdx.y * 64;
  for (int i = threadIdx.x; i < 4096; i += 256) {
    int r = i >> 6, c = i & 63;
    t[r][c] = src[(size_t)(r0 + r) * DM_ + c0 + c];
  }
  __syncthreads();
  for (int i = threadIdx.x; i < 4096; i += 256) {
    int n = i >> 6, kk = i & 63;
    dst[(size_t)(c0 + n) * DM_ + r0 + kk] = bfbits(t[kk][n]);
  }
}

__device__ __forceinline__ void gll16(const unsigned short* g, unsigned short* l) {
  __builtin_amdgcn_global_load_lds((const __attribute__((address_space(1))) void*)g,
                                   (__attribute__((address_space(3))) void*)l, 16, 0, 0);
}

// ---------------- 2-phase dbuf bf16 GEMM, 128x128 tile, BK=32 (r16 config) ----------------
template <int MODE>
__device__ __forceinline__ void gemm128_body(
    int bx, int by,
    const void* __restrict__ Av, const void* __restrict__ Btv, int K,
    const float* __restrict__ bias, const float* __restrict__ mem,
    const float* __restrict__ Wmm, const float* __restrict__ bmm,
    unsigned short* __restrict__ obf,
    unsigned short* Al, unsigned short* Bl) {
  constexpr bool AF32 = (MODE <= 1);
  constexpr bool BF32 = (MODE == 2);
  const int tid = threadIdx.x, lane = tid & 63, w = tid >> 6;
  const int wm = w >> 1, wn = w & 1;
  const int m0 = bx * 128, n0 = by * 128;
  const int lrow = lane >> 2, lcol = (lane & 3) * 8;
  const int fr = lane & 15, fk = (lane >> 4) * 8;
  constexpr int TSZ = 128 * 32;

  f32x4 acc[4][4] = {};

  const size_t aoff = (size_t)(m0 + w * 32 + lrow) * K + lcol;
  const size_t boff = (size_t)(n0 + w * 32 + lrow) * K + lcol;
  const unsigned short* agb = (const unsigned short*)Av + aoff;
  const float*          agf = (const float*)Av + aoff;
  const unsigned short* bgb = (const unsigned short*)Btv + boff;
  const float*          bgf = (const float*)Btv + boff;
  const int os0 = (w * 32 + lrow) * 32 + lcol;
  const int os1 = (w * 32 + lrow + 16) * 32 + lcol;
  const int oa0 = (w * 32) * 32, oa1 = (w * 32 + 16) * 32;
  const size_t s16K = (size_t)16 * K;

  float4 fa0, fa1, fa2, fa3;
  float4 fb0, fb1, fb2, fb3;

  const int KT = K >> 5;
  if constexpr (AF32) {
    fa0 = *(const float4*)agf; fa1 = *(const float4*)(agf + 4);
    fa2 = *(const float4*)(agf + s16K); fa3 = *(const float4*)(agf + s16K + 4);
    *(bf16x8*)(Al + os0) = cvt8(fa0, fa1);
    *(bf16x8*)(Al + os1) = cvt8(fa2, fa3);
    agf += 32;
    fa0 = *(const float4*)agf; fa1 = *(const float4*)(agf + 4);
    fa2 = *(const float4*)(agf + s16K); fa3 = *(const float4*)(agf + s16K + 4);
    agf += 32;
  } else {
    gll16(agb, Al + oa0); gll16(agb + s16K, Al + oa1);
    agb += 32;
  }
  if constexpr (BF32) {
    fb0 = *(const float4*)bgf; fb1 = *(const float4*)(bgf + 4);
    fb2 = *(const float4*)(bgf + s16K); fb3 = *(const float4*)(bgf + s16K + 4);
    *(bf16x8*)(Bl + os0) = cvt8(fb0, fb1);
    *(bf16x8*)(Bl + os1) = cvt8(fb2, fb3);
    bgf += 32;
    fb0 = *(const float4*)bgf; fb1 = *(const float4*)(bgf + 4);
    fb2 = *(const float4*)(bgf + s16K); fb3 = *(const float4*)(bgf + s16K + 4);
    bgf += 32;
  } else {
    gll16(bgb, Bl + oa0); gll16(bgb + s16K, Bl + oa1);
    bgb += 32;
  }
  __syncthreads();

  for (int kt = 0; kt < KT; ++kt) {
    const int cb = (kt & 1) * TSZ;
    const int sb = TSZ - cb;
    if (kt + 1 < KT) {
      if constexpr (AF32) {
        *(bf16x8*)(Al + sb + os0) = cvt8(fa0, fa1);
        *(bf16x8*)(Al + sb + os1) = cvt8(fa2, fa3);
      } else {
        gll16(agb, Al + sb + oa0); gll16(agb + s16K, Al + sb + oa1);
        agb += 32;
      }
      if constexpr (BF32) {
        *(bf16x8*)(Bl + sb + os0) = cvt8(fb0, fb1);
        *(bf16x8*)(Bl + sb + os1) = cvt8(fb2, fb3);
      } else {
        gll16(bgb, Bl + sb + oa0); gll16(bgb + s16K, Bl + sb + oa1);
        bgb += 32;
      }
    }
    if (kt + 2 < KT) {
      if constexpr (AF32) {
        fa0 = *(const float4*)agf; fa1 = *(const float4*)(agf + 4);
        fa2 = *(const float4*)(agf + s16K); fa3 = *(const float4*)(agf + s16K + 4);
        agf += 32;
      }
      if constexpr (BF32) {
        fb0 = *(const float4*)bgf; fb1 = *(const float4*)(bgf + 4);
        fb2 = *(const float4*)(bgf + s16K); fb3 = *(const float4*)(bgf + s16K + 4);
        bgf += 32;
      }
    }
    bf16x8 af[4], bfr[4];
#pragma unroll
    for (int i = 0; i < 4; ++i)
      af[i] = *(const bf16x8*)&Al[cb + (wm * 64 + i * 16 + fr) * 32 + fk];
#pragma unroll
    for (int j = 0; j < 4; ++j)
      bfr[j] = *(const bf16x8*)&Bl[cb + (wn * 64 + j * 16 + fr) * 32 + fk];
#pragma unroll
    for (int i = 0; i < 4; ++i)
#pragma unroll
      for (int j = 0; j < 4; ++j)
        acc[i][j] = __builtin_amdgcn_mfma_f32_16x16x32_bf16(af[i], bfr[j], acc[i][j], 0, 0, 0);
    __syncthreads();
  }

#pragma unroll
  for (int i = 0; i < 4; ++i) {
    const int rowb = m0 + wm * 64 + i * 16 + (lane >> 4) * 4;
#pragma unroll
    for (int j = 0; j < 4; ++j) {
      const int col = n0 + wn * 64 + j * 16 + fr;
#pragma unroll
      for (int r = 0; r < 4; ++r) {
        float v = acc[i][j][r];
        int rr = rowb + r;
        if (MODE == 0) {
          int b = rr >> 11, nq = rr & 2047, h = col >> 6, d = col & 63;
          float val = (v + bias[col]) * 0.180336884f;  // 0.125 * log2(e)
          obf[(((size_t)(b * H_ + h)) * NQ_ + nq) * 64 + d] = bfbits(val);
        } else if (MODE == 1) {
          int b = rr >> 11, nk = rr & 2047, h = col >> 6, d = col & 63;
          float gate = mem[b * NK_ + nk] * Wmm[col] + bmm[col];
          float val = (v + bias[col]) * gate;
          obf[(((size_t)(b * H_ + h)) * NK_ + nk) * 64 + d] = bfbits(val);
        } else {
          int b = col >> 11, key = col & 2047, h = rr >> 6, d = rr & 63;
          float gate = mem[b * NK_ + key] * Wmm[rr] + bmm[rr];
          float val = (v + bias[rr]) * gate;
          // swap bits 2<->3 of key so flash's 32x32 PV B-frag (P in regs) lines up with V
          int keyp = (key & ~12) | ((key & 4) << 1) | ((key & 8) >> 1);
          obf[(((size_t)(b * H_ + h)) * 64 + d) * NK_ + keyp] = bfbits(val);
        }
      }
    }
  }
}

// fused Q/K/V projections: 768 blocks (3/CU), f32 inputs read directly
__global__ __launch_bounds__(256) void gemm_qkv3(
    const float* __restrict__ queries, const float* __restrict__ keys,
    const float* __restrict__ values, const unsigned short* __restrict__ WvT,
    const unsigned short* __restrict__ WqT, const unsigned short* __restrict__ WkT,
    const float* __restrict__ bq, const float* __restrict__ bk, const float* __restrict__ bv,
    const float* __restrict__ mem, const float* __restrict__ Wmm, const float* __restrict__ bmm,
    unsigned short* __restrict__ Qp, unsigned short* __restrict__ Kp,
    unsigned short* __restrict__ VpT) {
  __shared__ unsigned short Al[2 * 128 * 32];
  __shared__ unsigned short Bl[2 * 128 * 32];
  const int gid = (blockIdx.x & 7) * 96 + (blockIdx.x >> 3);
  if (gid < 256) {
    gemm128_body<0>(gid >> 3, gid & 7, queries, WqT, 1024, bq, nullptr, nullptr, nullptr,
                    Qp, Al, Bl);
  } else if (gid < 512) {
    int bb = gid - 256;
    gemm128_body<1>(bb >> 3, bb & 7, keys, WkT, 1024, bk, mem, Wmm, bmm, Kp, Al, Bl);
  } else {
    int bb = gid - 512;
    gemm128_body<2>(bb & 7, bb >> 3, WvT, values, 1024, bv, mem, Wmm, bmm, VpT, Al, Bl);
  }
}

// ---------------- out projection: 64x128 tile, BK=32, 2-phase dbuf (512 blocks) ----------
__global__ __launch_bounds__(256) void gemm_out(
    const unsigned short* __restrict__ AO, const unsigned short* __restrict__ WoT,
    const float* __restrict__ bo, float* __restrict__ out) {
  __shared__ unsigned short Al[2 * 64 * 32];
  __shared__ unsigned short Bl[2 * 128 * 32];
  const int b = (blockIdx.x & 7) * 64 + (blockIdx.x >> 3);
  const int bx = b & 63, by = b >> 6;
  const int tid = threadIdx.x, lane = tid & 63, w = tid >> 6;
  const int wm = w >> 1, wn = w & 1;
  const int m0 = bx * 64, n0 = by * 128;
  const int lrow = lane >> 2, lcol = (lane & 3) * 8;
  const int fr = lane & 15, fk = (lane >> 4) * 8;
  const int K = 1024;
  constexpr int TA = 64 * 32, TB = 128 * 32;

  f32x4 acc[2][4] = {};

  const unsigned short* ag = AO + (size_t)(m0 + w * 16 + lrow) * K + lcol;
  const unsigned short* bg = WoT + (size_t)(n0 + w * 32 + lrow) * K + lcol;
  const int oa = (w * 16) * 32;
  const int ob0 = (w * 32) * 32, ob1 = (w * 32 + 16) * 32;
  const size_t s16K = (size_t)16 * K;

  gll16(ag, Al + oa);
  gll16(bg, Bl + ob0); gll16(bg + s16K, Bl + ob1);
  ag += 32; bg += 32;
  __syncthreads();

  for (int kt = 0; kt < 32; ++kt) {
    const int ca = (kt & 1) * TA, cbb = (kt & 1) * TB;
    const int sa = TA - ca, sbb = TB - cbb;
    if (kt + 1 < 32) {
      gll16(ag, Al + sa + oa);
      gll16(bg, Bl + sbb + ob0); gll16(bg + s16K, Bl + sbb + ob1);
      ag += 32; bg += 32;
    }
    bf16x8 af[2], bfr[4];
#pragma unroll
    for (int i = 0; i < 2; ++i)
      af[i] = *(const bf16x8*)&Al[ca + (wm * 32 + i * 16 + fr) * 32 + fk];
#pragma unroll
    for (int j = 0; j < 4; ++j)
      bfr[j] = *(const bf16x8*)&Bl[cbb + (wn * 64 + j * 16 + fr) * 32 + fk];
#pragma unroll
    for (int i = 0; i < 2; ++i)
#pragma unroll
      for (int j = 0; j < 4; ++j)
        acc[i][j] = __builtin_amdgcn_mfma_f32_16x16x32_bf16(af[i], bfr[j], acc[i][j], 0, 0, 0);
    __syncthreads();
  }

#pragma unroll
  for (int i = 0; i < 2; ++i) {
    const int rowb = m0 + wm * 32 + i * 16 + (lane >> 4) * 4;
#pragma unroll
    for (int j = 0; j < 4; ++j) {
      const int col = n0 + wn * 64 + j * 16 + fr;
#pragma unroll
      for (int r = 0; r < 4; ++r)
        out[(size_t)(rowb + r) * DM_ + col] = acc[i][j][r] + bo[col];
    }
  }
}

// ---------------- flash attention v15 (r20): gll16-staged K/V, chunk-swizzled ------------
__global__ __launch_bounds__(256, 2) void flash_attn(const unsigned short* __restrict__ Qp,
                                                     const unsigned short* __restrict__ Kp,
                                                     const unsigned short* __restrict__ VpT,
                                                     unsigned short* __restrict__ AO) {
  __shared__ unsigned short KsL[2][128 * 64];
  __shared__ unsigned short VsL[2][64 * 128];

  const int tid = threadIdx.x, lane = tid & 63, w = tid >> 6;
  const int gid = (blockIdx.x & 7) * 64 + (blockIdx.x >> 3);
  const int bh = gid >> 4;
  const int qt = gid & 15;
  const int r31 = lane & 31, hi2 = lane >> 5, rx7 = lane & 7;

  const unsigned short* qg = Qp + (((size_t)bh * NQ_) + qt * 128 + w * 32 + r31) * 64 + hi2 * 8;
  bf16x8 qf[4];
#pragma unroll
  for (int s = 0; s < 4; ++s) qf[s] = *(const bf16x8*)&qg[s * 16];

  int koff[4], voff[8];
#pragma unroll
  for (int s = 0; s < 4; ++s) koff[s] = ((s * 2 + hi2) ^ rx7) * 8;
#pragma unroll
  for (int ks = 0; ks < 8; ++ks) voff[ks] = ((ks * 2 + hi2) ^ rx7) * 8;

  const int kchunk = (lane & 7) ^ ((lane >> 3) & 7);
  const unsigned short* kgB = Kp + (size_t)bh * NK_ * 64
                              + (size_t)(w * 32 + (lane >> 3)) * 64 + kchunk * 8;
  const int vce = (lane & 15) ^ (lane >> 4);
  const int vco = (lane & 15) ^ (4 + (lane >> 4));
  const unsigned short* vgB = VpT + (size_t)bh * 64 * NK_
                              + (size_t)(w * 16 + (lane >> 4)) * NK_;

#pragma unroll
  for (int i = 0; i < 4; ++i) {
    gll16(kgB + i * 512, &KsL[0][(w * 32 + i * 8) * 64]);
    const int vc = (i & 1) ? vco : vce;
    gll16(vgB + (size_t)i * 4 * NK_ + vc * 8, &VsL[0][(w * 16 + i * 4) * 128]);
  }
  __syncthreads();

  f32x16 acc0 = {}, acc1 = {};
  float l_run = 0.0f;

  for (int kt = 0; kt < 16; ++kt) {
    const int cur = kt & 1;
    if (kt + 1 < 16) {
      const size_t ko = (size_t)(kt + 1) * 128 * 64;
      const int vko = (kt + 1) * 128;
#pragma unroll
      for (int i = 0; i < 4; ++i) {
        gll16(kgB + ko + i * 512, &KsL[cur ^ 1][(w * 32 + i * 8) * 64]);
        const int vc = (i & 1) ? vco : vce;
        gll16(vgB + (size_t)i * 4 * NK_ + vko + vc * 8, &VsL[cur ^ 1][(w * 16 + i * 4) * 128]);
      }
    }

    f32x16 sv[4] = {};
    __builtin_amdgcn_s_setprio(1);
#pragma unroll
    for (int s = 0; s < 4; ++s) {
#pragma unroll
      for (int kb = 0; kb < 4; ++kb) {
        bf16x8 ka = *(const bf16x8*)&KsL[cur][(kb * 32 + r31) * 64 + koff[s]];
        sv[kb] = __builtin_amdgcn_mfma_f32_32x32x16_bf16(ka, qf[s], sv[kb], 0, 0, 0);
      }
    }
    __builtin_amdgcn_s_setprio(0);

    float psp[4] = {0.f, 0.f, 0.f, 0.f};
    bf16x8 pb[8];
#pragma unroll
    for (int kb = 0; kb < 4; ++kb) {
#pragma unroll
      for (int g = 0; g < 16; ++g) {
        float p = __builtin_amdgcn_exp2f(sv[kb][g]);
        psp[kb] += p;
        pb[2 * kb + (g >> 3)][g & 7] = (__bf16)p;
      }
    }
    float ps = (psp[0] + psp[1]) + (psp[2] + psp[3]);
    ps += __shfl_xor(ps, 32);
    l_run += ps;

    __builtin_amdgcn_s_setprio(1);
#pragma unroll
    for (int ks = 0; ks < 8; ++ks) {
      bf16x8 va0 = *(const bf16x8*)&VsL[cur][r31 * 128 + voff[ks]];
      bf16x8 va1 = *(const bf16x8*)&VsL[cur][(32 + r31) * 128 + voff[ks]];
      acc0 = __builtin_amdgcn_mfma_f32_32x32x16_bf16(va0, pb[ks], acc0, 0, 0, 0);
      acc1 = __builtin_amdgcn_mfma_f32_32x32x16_bf16(va1, pb[ks], acc1, 0, 0, 0);
    }
    __builtin_amdgcn_s_setprio(0);

    __syncthreads();
  }

  const int b = bh >> 4, h = bh & 15;
  const float linv = 1.0f / l_run;
  const int qrow = qt * 128 + w * 32 + r31;
  const size_t rowbase = (((size_t)b * NQ_ + qrow) << 10) + h * 64;
#pragma unroll
  for (int c = 0; c < 4; ++c) {
    u16x4 o0, o1;
#pragma unroll
    for (int i = 0; i < 4; ++i) {
      o0[i] = bfbits(acc0[c * 4 + i] * linv);
      o1[i] = bfbits(acc1[c * 4 + i] * linv);
    }
    *(u16x4*)&AO[rowbase + 8 * c + 4 * hi2]      = o0;
    *(u16x4*)&AO[rowbase + 32 + 8 * c + 4 * hi2] = o1;
  }
}

extern "C" void kernel_launch(void* const* d_in, const int* in_sizes, int n_in,
                              void* d_out, int out_size, void* d_ws, size_t ws_size,
                              hipStream_t stream) {
  const float* queries = (const float*)d_in[0];
  const float* keys    = (const float*)d_in[1];
  const float* values  = (const float*)d_in[2];
  const float* memory  = (const float*)d_in[3];
  const float* Wq  = (const float*)d_in[4];
  const float* bq  = (const float*)d_in[5];
  const float* Wk  = (const float*)d_in[6];
  const float* bk  = (const float*)d_in[7];
  const float* Wv  = (const float*)d_in[8];
  const float* bv  = (const float*)d_in[9];
  const float* Wo  = (const float*)d_in[10];
  const float* bo  = (const float*)d_in[11];
  const float* Wmm = (const float*)d_in[12];
  const float* bmm = (const float*)d_in[13];

  char* ws = (char*)d_ws;
  const size_t MB = 1024 * 1024;
  unsigned short* AO  = (unsigned short*)(ws);
  unsigned short* WqT = (unsigned short*)(ws + 8 * MB);
  unsigned short* WkT = (unsigned short*)(ws + 10 * MB);
  unsigned short* WvT = (unsigned short*)(ws + 12 * MB);
  unsigned short* WoT = (unsigned short*)(ws + 14 * MB);
  unsigned short* Qp  = (unsigned short*)(ws + 16 * MB);
  unsigned short* Kp  = (unsigned short*)(ws + 24 * MB);
  unsigned short* VpT = (unsigned short*)(ws + 32 * MB);

  prep<<<dim3(16, 16, 4), 256, 0, stream>>>(Wq, Wk, Wv, Wo, WqT, WkT, WvT, WoT);

  gemm_qkv3<<<768, 256, 0, stream>>>(queries, keys, values, WvT, WqT, WkT,
                                     bq, bk, bv, memory, Wmm, bmm, Qp, Kp, VpT);

  flash_attn<<<512, 256, 0, stream>>>(Qp, Kp, VpT, AO);

  gemm_out<<<512, 256, 0, stream>>>(AO, WoT, bo, (float*)d_out);
}